// Round 5
// baseline (136.888 us; speedup 1.0000x reference)
//
#include <hip/hip_runtime.h>
#include <hip/hip_bf16.h>
#include <math.h>

#define BB 2
#define TT 2048
#define CCH 1024
#define HH 16
#define DD 64
#define BT (BB*TT)     // 4096
#define N3 (3*CCH)     // 3072
#define NJOBS 40       // sum over 16 q-tiles of ceil((qt+1)/4)

typedef __attribute__((ext_vector_type(8))) short short8;
typedef __attribute__((ext_vector_type(4))) float f32x4;
typedef __attribute__((ext_vector_type(16))) float f32x16;

__device__ __forceinline__ unsigned short f2bf(float f) {
  unsigned int u = __float_as_uint(f);
  unsigned int r = (u + 0x7FFFu + ((u >> 16) & 1u)) >> 16;  // RNE
  return (unsigned short)r;
}
__device__ __forceinline__ float bf2f(unsigned short u) {
  return __uint_as_float(((unsigned int)u) << 16);
}
__device__ __forceinline__ int cvtpk(float lo, float hi) {
  int r;
  asm("v_cvt_pk_bf16_f32 %0, %1, %2" : "=v"(r) : "v"(lo), "v"(hi));
  return r;
}
__device__ __forceinline__ void plswap(int &a, int &b) {
  asm("v_permlane32_swap_b32 %0, %1" : "+v"(a), "+v"(b));
}
__device__ __forceinline__ void gload_lds16(const unsigned short* g, unsigned short* l) {
  __builtin_amdgcn_global_load_lds((const __attribute__((address_space(1))) void*)g,
                                   (__attribute__((address_space(3))) void*)l, 16, 0, 0);
}
__device__ __forceinline__ float fmax3(float a, float b, float c) {
  return fmaxf(fmaxf(a, b), c);   // fuses to v_max3_f32
}
// job-base for q-tile qt
__device__ __forceinline__ int jbase(int qt) {
  int a = qt >> 2, b = qt & 3;
  return qt + 2 * a * (a - 1) + a * b;
}

// ---------------- f32 -> bf16 flat convert ----------------
__global__ __launch_bounds__(256) void k_convert(const float* __restrict__ in,
                                                 unsigned short* __restrict__ out, int n8) {
  int i = blockIdx.x * 256 + threadIdx.x;
  if (i < n8) {
    const float4 a = *(const float4*)(in + (size_t)i * 8);
    const float4 b = *(const float4*)(in + (size_t)i * 8 + 4);
    short8 v;
    v[0] = f2bf(a.x); v[1] = f2bf(a.y); v[2] = f2bf(a.z); v[3] = f2bf(a.w);
    v[4] = f2bf(b.x); v[5] = f2bf(b.y); v[6] = f2bf(b.z); v[7] = f2bf(b.w);
    *(short8*)(out + (size_t)i * 8) = v;
  }
}

// ---------------- transpose + f32->bf16 convert: out[c][r] = in[r][c] ----------------
__global__ __launch_bounds__(256) void k_transpose_cvt(const float* __restrict__ in,
                                                       unsigned short* __restrict__ out,
                                                       int R, int Cn) {
  __shared__ float tile[32][33];
  int tc = blockIdx.x * 32;
  int tr = blockIdx.y * 32;
  int lx = threadIdx.x & 31;
  int ly = threadIdx.x >> 5;  // 0..7
#pragma unroll
  for (int i = 0; i < 32; i += 8)
    tile[ly + i][lx] = in[(size_t)(tr + ly + i) * Cn + tc + lx];
  __syncthreads();
#pragma unroll
  for (int i = 0; i < 32; i += 8)
    out[(size_t)(tc + ly + i) * R + tr + lx] = f2bf(tile[lx][ly + i]);
}

// ---------------- QKV GEMM (m97 pattern): Xb bf16 @ Wt bf16 -> Q(scaled),K,Vt bf16 ----------------
__global__ __launch_bounds__(256) void k_qkv_gemm(const unsigned short* __restrict__ Xb,
                                                  const unsigned short* __restrict__ Wt,
                                                  const float* __restrict__ bias,
                                                  unsigned short* __restrict__ Qo,
                                                  unsigned short* __restrict__ Ko,
                                                  unsigned short* __restrict__ Vto) {
  __shared__ __align__(16) unsigned short As[128 * 32];
  __shared__ __align__(16) unsigned short Bs[128 * 32];
  int tid = threadIdx.x;
  int mb = blockIdx.x * 128;
  int nb = blockIdx.y * 128;
  int wid = tid >> 6, lane = tid & 63;
  int wr = (wid >> 1) * 64, wc = (wid & 1) * 64;
  int l15 = lane & 15, l4 = lane >> 4;
  int l16 = lane >> 2, lc = (lane & 3) * 8;   // staging row-within-16 / col
  f32x4 acc[4][4];
#pragma unroll
  for (int a = 0; a < 4; ++a)
#pragma unroll
    for (int b = 0; b < 4; ++b)
#pragma unroll
      for (int j = 0; j < 4; ++j) acc[a][b][j] = 0.0f;

  for (int kb = 0; kb < CCH; kb += 32) {
#pragma unroll
    for (int i = 0; i < 2; ++i) {
      int arow = wid * 32 + i * 16;
      gload_lds16(Xb + (size_t)(mb + arow + l16) * CCH + kb + lc, &As[arow * 32]);
      gload_lds16(Wt + (size_t)(nb + arow + l16) * CCH + kb + lc, &Bs[arow * 32]);
    }
    __syncthreads();
    short8 af[4], bfr[4];
#pragma unroll
    for (int mt = 0; mt < 4; ++mt) af[mt] = *(const short8*)(&As[(wr + mt * 16 + l15) * 32 + l4 * 8]);
#pragma unroll
    for (int nt = 0; nt < 4; ++nt) bfr[nt] = *(const short8*)(&Bs[(wc + nt * 16 + l15) * 32 + l4 * 8]);
#pragma unroll
    for (int mt = 0; mt < 4; ++mt)
#pragma unroll
      for (int nt = 0; nt < 4; ++nt)
        acc[mt][nt] = __builtin_amdgcn_mfma_f32_16x16x32_bf16(af[mt], bfr[nt], acc[mt][nt], 0, 0, 0);
    __syncthreads();
  }

#pragma unroll
  for (int mt = 0; mt < 4; ++mt) {
#pragma unroll
    for (int nt = 0; nt < 4; ++nt) {
      int gcol = nb + wc + nt * 16 + l15;        // 0..3071
      int which = gcol >> 10;
      int cc = gcol & 1023;
      int h = cc >> 6, d = cc & 63;
      float bv = bias[gcol];
#pragma unroll
      for (int j = 0; j < 4; ++j) {
        int grow = mb + wr + mt * 16 + l4 * 4 + j;  // 0..4095
        int b = grow >> 11, t = grow & 2047;
        float v = acc[mt][nt][j] + bv;
        size_t bh = (size_t)(b * HH + h);
        // fold sm_scale AND log2(e): softmax runs in exp2 domain
        if (which == 0)      Qo[(bh * TT + t) * DD + d] = f2bf(v * 0.18033688f);
        else if (which == 1) Ko[(bh * TT + t) * DD + d] = f2bf(v);
        else                 Vto[(bh * DD + d) * TT + t] = f2bf(v);
      }
    }
  }
}

// ---------------- causal flash attention: swapped QK^T, in-register softmax (exp2 domain) ----------------
__global__ __launch_bounds__(256) void k_attn(const unsigned short* __restrict__ Qb,
                                              const unsigned short* __restrict__ Kb,
                                              const unsigned short* __restrict__ Vtb,
                                              unsigned short* __restrict__ PO,
                                              float* __restrict__ Pm,
                                              float* __restrict__ Pl) {
  __shared__ unsigned short Ks[2][64 * 64];   // [kv][d], XOR-swizzled 16B chunks
  __shared__ unsigned short Vs[2][64 * 64];   // [d][kv], XOR-swizzled 16B chunks
  int tid = threadIdx.x;
  int jx = NJOBS - 1 - blockIdx.x;            // LPT: biggest jobs dispatched first
  int bh = blockIdx.y;
  int qt = 0;
#pragma unroll
  for (int q = 1; q < 16; ++q)
    if (jx >= jbase(q)) qt = q;
  int chunk = jx - jbase(qt);
  int t0 = chunk * 8;
  int t1 = min(t0 + 8, (qt + 1) * 2);
  size_t job = (size_t)bh * NJOBS + jx;

  const unsigned short* Qp = Qb + (size_t)bh * TT * DD;
  const unsigned short* Kp = Kb + (size_t)bh * TT * DD;
  const unsigned short* Vp = Vtb + (size_t)bh * DD * TT;
  int wid = tid >> 6, lane = tid & 63;
  int l31 = lane & 31, h = lane >> 5;
  int q0 = qt * 128 + wid * 32;
  int qrow = q0 + l31;

  short8 qf[4];
#pragma unroll
  for (int m = 0; m < 4; ++m)
    qf[m] = *(const short8*)(Qp + (size_t)qrow * DD + m * 16 + h * 8);

  // persistent zero vector: C-operand for first QK MFMA (kills per-tile v_mov init)
  f32x16 zv;
#pragma unroll
  for (int r = 0; r < 16; ++r) zv[r] = 0.0f;

  f32x16 po[2];
  po[0] = zv; po[1] = zv;
  float mrun = -1e30f, lrun = 0.0f;

  short8 rk[2], rv[2];
#pragma unroll
  for (int i = 0; i < 2; ++i) {
    int idx = tid + i * 256;
    int row = idx >> 3, c = idx & 7;
    rk[i] = *(const short8*)(Kp + (size_t)(t0 * 64 + row) * DD + c * 8);
    rv[i] = *(const short8*)(Vp + (size_t)row * TT + t0 * 64 + c * 8);
  }
#pragma unroll
  for (int i = 0; i < 2; ++i) {
    int idx = tid + i * 256;
    int row = idx >> 3, c = idx & 7;
    int off = row * 64 + ((c ^ (row & 7)) * 8);
    *(short8*)(&Ks[0][off]) = rk[i];
    *(short8*)(&Vs[0][off]) = rv[i];
  }

  int buf = 0;
  for (int t = t0; t < t1; ++t) {
    __syncthreads();
    int kvb = t * 64;
    bool havenext = (t + 1 < t1);
    if (havenext) {
      int kvb2 = (t + 1) * 64;
#pragma unroll
      for (int i = 0; i < 2; ++i) {
        int idx = tid + i * 256;
        int row = idx >> 3, c = idx & 7;
        rk[i] = *(const short8*)(Kp + (size_t)(kvb2 + row) * DD + c * 8);
        rv[i] = *(const short8*)(Vp + (size_t)row * TT + kvb2 + c * 8);
      }
    }

    if (kvb <= q0 + 31) {
      f32x16 st[2];
      __builtin_amdgcn_s_setprio(1);
#pragma unroll
      for (int t32 = 0; t32 < 2; ++t32) {
        int row = t32 * 32 + l31;
        {
          int off = row * 64 + ((h ^ (row & 7)) * 8);
          short8 kf = *(const short8*)(&Ks[buf][off]);
          st[t32] = __builtin_amdgcn_mfma_f32_32x32x16_bf16(kf, qf[0], zv, 0, 0, 0);
        }
#pragma unroll
        for (int m = 1; m < 4; ++m) {
          int off = row * 64 + (((2 * m + h) ^ (row & 7)) * 8);
          short8 kf = *(const short8*)(&Ks[buf][off]);
          st[t32] = __builtin_amdgcn_mfma_f32_32x32x16_bf16(kf, qf[m], st[t32], 0, 0, 0);
        }
      }
      __builtin_amdgcn_s_setprio(0);

      if (kvb + 63 > q0) {
#pragma unroll
        for (int t32 = 0; t32 < 2; ++t32)
#pragma unroll
          for (int r = 0; r < 16; ++r) {
            int kvg = kvb + t32 * 32 + (r & 3) + 8 * (r >> 2) + 4 * h;
            if (kvg > qrow) st[t32][r] = -1e30f;
          }
      }

      // row max: 4-chain v_max3 tree over 32 values, then cross-half
      float A = st[0][0], B = st[0][1], C = st[0][2], Dv = st[0][3];
#pragma unroll
      for (int r = 4; r < 16; r += 4) {
        A = fmax3(A, st[0][r], st[0][r + 1]);
        B = fmax3(B, st[0][r + 2], st[0][r + 3]);
        C = fmax3(C, st[1][r - 4], st[1][r - 3]);
        Dv = fmax3(Dv, st[1][r - 2], st[1][r - 1]);
      }
      C = fmax3(C, st[1][12], st[1][13]);
      Dv = fmax3(Dv, st[1][14], st[1][15]);
      float mx = fmaxf(fmax3(A, B, C), Dv);
      mx = fmaxf(mx, __shfl_xor(mx, 32));

      if (__any(mx - mrun > 8.0f)) {     // log2 units
        float mnew = fmaxf(mrun, mx);
        float alpha = exp2f(mrun - mnew);
        lrun *= alpha;
#pragma unroll
        for (int dt = 0; dt < 2; ++dt)
#pragma unroll
          for (int r = 0; r < 16; ++r) po[dt][r] *= alpha;
        mrun = mnew;
      }

      float sum = 0.0f;
#pragma unroll
      for (int t32 = 0; t32 < 2; ++t32)
#pragma unroll
        for (int r = 0; r < 16; ++r) {
          float p = exp2f(st[t32][r] - mrun);
          st[t32][r] = p;
          sum += p;
        }
      sum += __shfl_xor(sum, 32);
      lrun += sum;

      short8 pf[4];
#pragma unroll
      for (int g = 0; g < 4; ++g) {
        int t32 = g >> 1, r0 = (g & 1) * 8;
        int a = cvtpk(st[t32][r0 + 0], st[t32][r0 + 1]);
        int b = cvtpk(st[t32][r0 + 4], st[t32][r0 + 5]);
        plswap(a, b);
        int c = cvtpk(st[t32][r0 + 2], st[t32][r0 + 3]);
        int d = cvtpk(st[t32][r0 + 6], st[t32][r0 + 7]);
        plswap(c, d);
        union { int w[4]; short8 s; } u;
        u.w[0] = a; u.w[1] = c; u.w[2] = b; u.w[3] = d;
        pf[g] = u.s;
      }

      __builtin_amdgcn_s_setprio(1);
#pragma unroll
      for (int dt = 0; dt < 2; ++dt) {
#pragma unroll
        for (int g = 0; g < 4; ++g) {
          int row = dt * 32 + l31;
          int off = row * 64 + (((2 * g + h) ^ (row & 7)) * 8);
          short8 vf = *(const short8*)(&Vs[buf][off]);
          po[dt] = __builtin_amdgcn_mfma_f32_32x32x16_bf16(vf, pf[g], po[dt], 0, 0, 0);
        }
      }
      __builtin_amdgcn_s_setprio(0);
    }

    if (havenext) {
#pragma unroll
      for (int i = 0; i < 2; ++i) {
        int idx = tid + i * 256;
        int row = idx >> 3, c = idx & 7;
        int off = row * 64 + ((c ^ (row & 7)) * 8);
        *(short8*)(&Ks[buf ^ 1][off]) = rk[i];
        *(short8*)(&Vs[buf ^ 1][off]) = rv[i];
      }
    }
    buf ^= 1;
  }

  int wrow = wid * 32 + l31;
  size_t pobase = (job * 128 + wrow) * 64;
#pragma unroll
  for (int dt = 0; dt < 2; ++dt)
#pragma unroll
    for (int r = 0; r < 16; r += 2) {
      int d = dt * 32 + (r & 3) + 8 * (r >> 2) + 4 * h;
      int w = cvtpk(po[dt][r], po[dt][r + 1]);
      *(int*)(PO + pobase + d) = w;
    }
  if (h == 0) {
    Pm[job * 128 + wrow] = mrun;
    Pl[job * 128 + wrow] = lrun;
  }
}

// ---------------- combine partials -> Yb bf16 (exp2 domain) ----------------
__global__ __launch_bounds__(256) void k_attn_combine(const unsigned short* __restrict__ PO,
                                                      const float* __restrict__ Pm,
                                                      const float* __restrict__ Pl,
                                                      unsigned short* __restrict__ Y) {
  int qt = blockIdx.x, bh = blockIdx.y;
  int nc = (qt >> 2) + 1;
  size_t job0 = (size_t)bh * NJOBS + jbase(qt);
  int tid = threadIdx.x;
  int row = tid >> 1, half = tid & 1;

  float m[4], l[4];
  float M = -1e30f;
  for (int c = 0; c < nc; ++c) {
    m[c] = Pm[(job0 + c) * 128 + row];
    l[c] = Pl[(job0 + c) * 128 + row];
    M = fmaxf(M, m[c]);
  }
  float L = 0.0f, w[4];
  for (int c = 0; c < nc; ++c) {
    w[c] = exp2f(m[c] - M);
    L += l[c] * w[c];
  }
  float inv = 1.0f / L;

  float acc[32];
#pragma unroll
  for (int j = 0; j < 32; ++j) acc[j] = 0.0f;
  for (int c = 0; c < nc; ++c) {
    const unsigned short* p = PO + ((job0 + c) * 128 + row) * 64 + half * 32;
    float wc = w[c];
#pragma unroll
    for (int k = 0; k < 4; ++k) {
      short8 v = *(const short8*)(p + k * 8);
#pragma unroll
      for (int j = 0; j < 8; ++j) acc[k * 8 + j] += wc * bf2f((unsigned short)v[j]);
    }
  }
  int b = bh >> 4, hh = bh & 15;
  int t = qt * 128 + row;
  unsigned short* yp = Y + ((size_t)(b * TT + t)) * CCH + hh * DD + half * 32;
#pragma unroll
  for (int k = 0; k < 4; ++k) {
    short8 wv;
#pragma unroll
    for (int j = 0; j < 8; ++j) wv[j] = (short)f2bf(acc[k * 8 + j] * inv);
    *(short8*)(yp + k * 8) = wv;
  }
}

// ---------------- proj GEMM (m97 pattern): Yb bf16 @ Wt_proj bf16 + bias -> f32 out ----------------
__global__ __launch_bounds__(256) void k_proj_gemm(const unsigned short* __restrict__ Yb,
                                                   const unsigned short* __restrict__ Wt,
                                                   const float* __restrict__ bias,
                                                   float* __restrict__ Out) {
  __shared__ __align__(16) unsigned short As[128 * 32];
  __shared__ __align__(16) unsigned short Bs[128 * 32];
  int tid = threadIdx.x;
  int mb = blockIdx.x * 128;
  int nb = blockIdx.y * 128;
  int wid = tid >> 6, lane = tid & 63;
  int wr = (wid >> 1) * 64, wc = (wid & 1) * 64;
  int l15 = lane & 15, l4 = lane >> 4;
  int l16 = lane >> 2, lc = (lane & 3) * 8;
  f32x4 acc[4][4];
#pragma unroll
  for (int a = 0; a < 4; ++a)
#pragma unroll
    for (int b = 0; b < 4; ++b)
#pragma unroll
      for (int j = 0; j < 4; ++j) acc[a][b][j] = 0.0f;

  for (int kb = 0; kb < CCH; kb += 32) {
#pragma unroll
    for (int i = 0; i < 2; ++i) {
      int arow = wid * 32 + i * 16;
      gload_lds16(Yb + (size_t)(mb + arow + l16) * CCH + kb + lc, &As[arow * 32]);
      gload_lds16(Wt + (size_t)(nb + arow + l16) * CCH + kb + lc, &Bs[arow * 32]);
    }
    __syncthreads();
    short8 af[4], bfr[4];
#pragma unroll
    for (int mt = 0; mt < 4; ++mt) af[mt] = *(const short8*)(&As[(wr + mt * 16 + l15) * 32 + l4 * 8]);
#pragma unroll
    for (int nt = 0; nt < 4; ++nt) bfr[nt] = *(const short8*)(&Bs[(wc + nt * 16 + l15) * 32 + l4 * 8]);
#pragma unroll
    for (int mt = 0; mt < 4; ++mt)
#pragma unroll
      for (int nt = 0; nt < 4; ++nt)
        acc[mt][nt] = __builtin_amdgcn_mfma_f32_16x16x32_bf16(af[mt], bfr[nt], acc[mt][nt], 0, 0, 0);
    __syncthreads();
  }

#pragma unroll
  for (int mt = 0; mt < 4; ++mt) {
#pragma unroll
    for (int nt = 0; nt < 4; ++nt) {
      int gcol = nb + wc + nt * 16 + l15;
      float bv = bias[gcol];
#pragma unroll
      for (int j = 0; j < 4; ++j) {
        int grow = mb + wr + mt * 16 + l4 * 4 + j;
        Out[(size_t)grow * CCH + gcol] = acc[mt][nt][j] + bv;
      }
    }
  }
}

extern "C" void kernel_launch(void* const* d_in, const int* in_sizes, int n_in,
                              void* d_out, int out_size, void* d_ws, size_t ws_size,
                              hipStream_t stream) {
  const float* x      = (const float*)d_in[0];
  const float* W_qkv  = (const float*)d_in[1];
  const float* b_qkv  = (const float*)d_in[2];
  const float* W_proj = (const float*)d_in[3];
  const float* b_proj = (const float*)d_in[4];
  float* out = (float*)d_out;

  char* ws = (char*)d_ws;
  size_t off = 0;
  unsigned short* Wt_qkv  = (unsigned short*)(ws + off); off += (size_t)N3 * CCH * 2;   // 6.3 MB
  unsigned short* Wt_proj = (unsigned short*)(ws + off); off += (size_t)CCH * CCH * 2;  // 2.1 MB
  unsigned short* Xb      = (unsigned short*)(ws + off); off += (size_t)BT * CCH * 2;   // 8.4 MB
  unsigned short* Qb      = (unsigned short*)(ws + off); off += (size_t)BT * CCH * 2;   // 8.4 MB
  unsigned short* Kb      = (unsigned short*)(ws + off); off += (size_t)BT * CCH * 2;   // 8.4 MB
  unsigned short* Vt      = (unsigned short*)(ws + off); off += (size_t)BT * CCH * 2;   // 8.4 MB
  unsigned short* Yb      = (unsigned short*)(ws + off); off += (size_t)BT * CCH * 2;   // 8.4 MB
  unsigned short* PO      = (unsigned short*)(ws + off); off += (size_t)32 * NJOBS * 128 * 64 * 2; // 21 MB
  float*          Pm      = (float*)(ws + off);          off += (size_t)32 * NJOBS * 128 * 4;
  float*          Pl      = (float*)(ws + off);          off += (size_t)32 * NJOBS * 128 * 4;

  k_convert<<<dim3(BT * CCH / 8 / 256), 256, 0, stream>>>(x, Xb, BT * CCH / 8);
  k_transpose_cvt<<<dim3(N3 / 32, CCH / 32), 256, 0, stream>>>(W_qkv, Wt_qkv, CCH, N3);
  k_transpose_cvt<<<dim3(CCH / 32, CCH / 32), 256, 0, stream>>>(W_proj, Wt_proj, CCH, CCH);
  k_qkv_gemm<<<dim3(BT / 128, N3 / 128), 256, 0, stream>>>(Xb, Wt_qkv, b_qkv, Qb, Kb, Vt);
  k_attn<<<dim3(NJOBS, BB * HH), 256, 0, stream>>>(Qb, Kb, Vt, PO, Pm, Pl);
  k_attn_combine<<<dim3(TT / 128, BB * HH), 256, 0, stream>>>(PO, Pm, Pl, Yb);
  k_proj_gemm<<<dim3(BT / 128, CCH / 128), 256, 0, stream>>>(Yb, Wt_proj, b_proj, out);
}

// Round 6
// 130.211 us; speedup vs baseline: 1.0513x; 1.0513x over previous
//
#include <hip/hip_runtime.h>
#include <hip/hip_bf16.h>
#include <math.h>

#define BB 2
#define TT 2048
#define CCH 1024
#define HH 16
#define DD 64
#define BT (BB*TT)     // 4096
#define N3 (3*CCH)     // 3072
#define NJOBS 40       // sum over 16 q-tiles of ceil((qt+1)/4)

typedef __attribute__((ext_vector_type(8))) short short8;
typedef __attribute__((ext_vector_type(4))) float f32x4;
typedef __attribute__((ext_vector_type(16))) float f32x16;

__device__ __forceinline__ unsigned short f2bf(float f) {
  unsigned int u = __float_as_uint(f);
  unsigned int r = (u + 0x7FFFu + ((u >> 16) & 1u)) >> 16;  // RNE
  return (unsigned short)r;
}
__device__ __forceinline__ float bf2f(unsigned short u) {
  return __uint_as_float(((unsigned int)u) << 16);
}
__device__ __forceinline__ int cvtpk(float lo, float hi) {
  int r;
  asm("v_cvt_pk_bf16_f32 %0, %1, %2" : "=v"(r) : "v"(lo), "v"(hi));
  return r;
}
__device__ __forceinline__ void plswap(int &a, int &b) {
  asm("v_permlane32_swap_b32 %0, %1" : "+v"(a), "+v"(b));
}
__device__ __forceinline__ float fexp2(float x) {   // native v_exp_f32: 2^x, 1 inst
  float r;
  asm("v_exp_f32 %0, %1" : "=v"(r) : "v"(x));
  return r;
}
__device__ __forceinline__ void gload_lds16(const unsigned short* g, unsigned short* l) {
  __builtin_amdgcn_global_load_lds((const __attribute__((address_space(1))) void*)g,
                                   (__attribute__((address_space(3))) void*)l, 16, 0, 0);
}
__device__ __forceinline__ float fmax3(float a, float b, float c) {
  return fmaxf(fmaxf(a, b), c);   // fuses to v_max3_f32
}
// job-base for q-tile qt
__device__ __forceinline__ int jbase(int qt) {
  int a = qt >> 2, b = qt & 3;
  return qt + 2 * a * (a - 1) + a * b;
}

// ---------------- f32 -> bf16 flat convert ----------------
__global__ __launch_bounds__(256) void k_convert(const float* __restrict__ in,
                                                 unsigned short* __restrict__ out, int n8) {
  int i = blockIdx.x * 256 + threadIdx.x;
  if (i < n8) {
    const float4 a = *(const float4*)(in + (size_t)i * 8);
    const float4 b = *(const float4*)(in + (size_t)i * 8 + 4);
    short8 v;
    v[0] = f2bf(a.x); v[1] = f2bf(a.y); v[2] = f2bf(a.z); v[3] = f2bf(a.w);
    v[4] = f2bf(b.x); v[5] = f2bf(b.y); v[6] = f2bf(b.z); v[7] = f2bf(b.w);
    *(short8*)(out + (size_t)i * 8) = v;
  }
}

// ---------------- transpose + f32->bf16 convert: out[c][r] = in[r][c] ----------------
__global__ __launch_bounds__(256) void k_transpose_cvt(const float* __restrict__ in,
                                                       unsigned short* __restrict__ out,
                                                       int R, int Cn) {
  __shared__ float tile[32][33];
  int tc = blockIdx.x * 32;
  int tr = blockIdx.y * 32;
  int lx = threadIdx.x & 31;
  int ly = threadIdx.x >> 5;  // 0..7
#pragma unroll
  for (int i = 0; i < 32; i += 8)
    tile[ly + i][lx] = in[(size_t)(tr + ly + i) * Cn + tc + lx];
  __syncthreads();
#pragma unroll
  for (int i = 0; i < 32; i += 8)
    out[(size_t)(tc + ly + i) * R + tr + lx] = f2bf(tile[lx][ly + i]);
}

// ---------------- QKV GEMM (m97 pattern): Xb bf16 @ Wt bf16 -> Q(scaled),K,Vt bf16 ----------------
__global__ __launch_bounds__(256) void k_qkv_gemm(const unsigned short* __restrict__ Xb,
                                                  const unsigned short* __restrict__ Wt,
                                                  const float* __restrict__ bias,
                                                  unsigned short* __restrict__ Qo,
                                                  unsigned short* __restrict__ Ko,
                                                  unsigned short* __restrict__ Vto) {
  __shared__ __align__(16) unsigned short As[128 * 32];
  __shared__ __align__(16) unsigned short Bs[128 * 32];
  int tid = threadIdx.x;
  int mb = blockIdx.x * 128;
  int nb = blockIdx.y * 128;
  int wid = tid >> 6, lane = tid & 63;
  int wr = (wid >> 1) * 64, wc = (wid & 1) * 64;
  int l15 = lane & 15, l4 = lane >> 4;
  int l16 = lane >> 2, lc = (lane & 3) * 8;   // staging row-within-16 / col
  f32x4 acc[4][4];
#pragma unroll
  for (int a = 0; a < 4; ++a)
#pragma unroll
    for (int b = 0; b < 4; ++b)
#pragma unroll
      for (int j = 0; j < 4; ++j) acc[a][b][j] = 0.0f;

  for (int kb = 0; kb < CCH; kb += 32) {
#pragma unroll
    for (int i = 0; i < 2; ++i) {
      int arow = wid * 32 + i * 16;
      gload_lds16(Xb + (size_t)(mb + arow + l16) * CCH + kb + lc, &As[arow * 32]);
      gload_lds16(Wt + (size_t)(nb + arow + l16) * CCH + kb + lc, &Bs[arow * 32]);
    }
    __syncthreads();
    short8 af[4], bfr[4];
#pragma unroll
    for (int mt = 0; mt < 4; ++mt) af[mt] = *(const short8*)(&As[(wr + mt * 16 + l15) * 32 + l4 * 8]);
#pragma unroll
    for (int nt = 0; nt < 4; ++nt) bfr[nt] = *(const short8*)(&Bs[(wc + nt * 16 + l15) * 32 + l4 * 8]);
#pragma unroll
    for (int mt = 0; mt < 4; ++mt)
#pragma unroll
      for (int nt = 0; nt < 4; ++nt)
        acc[mt][nt] = __builtin_amdgcn_mfma_f32_16x16x32_bf16(af[mt], bfr[nt], acc[mt][nt], 0, 0, 0);
    __syncthreads();
  }

#pragma unroll
  for (int mt = 0; mt < 4; ++mt) {
#pragma unroll
    for (int nt = 0; nt < 4; ++nt) {
      int gcol = nb + wc + nt * 16 + l15;        // 0..3071
      int which = gcol >> 10;
      int cc = gcol & 1023;
      int h = cc >> 6, d = cc & 63;
      float bv = bias[gcol];
#pragma unroll
      for (int j = 0; j < 4; ++j) {
        int grow = mb + wr + mt * 16 + l4 * 4 + j;  // 0..4095
        int b = grow >> 11, t = grow & 2047;
        float v = acc[mt][nt][j] + bv;
        size_t bh = (size_t)(b * HH + h);
        // fold sm_scale AND log2(e): softmax runs in exp2 domain
        if (which == 0)      Qo[(bh * TT + t) * DD + d] = f2bf(v * 0.18033688f);
        else if (which == 1) Ko[(bh * TT + t) * DD + d] = f2bf(v);
        else                 Vto[(bh * DD + d) * TT + t] = f2bf(v);
      }
    }
  }
}

// ---------------- causal flash attention: swapped QK^T, in-register softmax (exp2 domain) ----------------
__global__ __launch_bounds__(256) void k_attn(const unsigned short* __restrict__ Qb,
                                              const unsigned short* __restrict__ Kb,
                                              const unsigned short* __restrict__ Vtb,
                                              unsigned short* __restrict__ PO,
                                              float* __restrict__ Pm,
                                              float* __restrict__ Pl) {
  __shared__ unsigned short Ks[2][64 * 64];   // [kv][d], XOR-swizzled 16B chunks
  __shared__ unsigned short Vs[2][64 * 64];   // [d][kv], XOR-swizzled 16B chunks
  int tid = threadIdx.x;
  int jx = blockIdx.x;
  int bh = blockIdx.y;
  int qt = 0;
#pragma unroll
  for (int q = 1; q < 16; ++q)
    if (jx >= jbase(q)) qt = q;
  int chunk = jx - jbase(qt);
  int t0 = chunk * 8;
  int t1 = min(t0 + 8, (qt + 1) * 2);
  size_t job = (size_t)bh * NJOBS + jx;

  const unsigned short* Qp = Qb + (size_t)bh * TT * DD;
  const unsigned short* Kp = Kb + (size_t)bh * TT * DD;
  const unsigned short* Vp = Vtb + (size_t)bh * DD * TT;
  int wid = tid >> 6, lane = tid & 63;
  int l31 = lane & 31, h = lane >> 5;
  int q0 = qt * 128 + wid * 32;
  int qrow = q0 + l31;

  short8 qf[4];
#pragma unroll
  for (int m = 0; m < 4; ++m)
    qf[m] = *(const short8*)(Qp + (size_t)qrow * DD + m * 16 + h * 8);

  // persistent zero vector: C-operand for first QK MFMA (kills per-tile v_mov init)
  f32x16 zv;
#pragma unroll
  for (int r = 0; r < 16; ++r) zv[r] = 0.0f;

  f32x16 po[2];
  po[0] = zv; po[1] = zv;
  float mrun = -1e30f, lrun = 0.0f;

  short8 rk[2], rv[2];
#pragma unroll
  for (int i = 0; i < 2; ++i) {
    int idx = tid + i * 256;
    int row = idx >> 3, c = idx & 7;
    rk[i] = *(const short8*)(Kp + (size_t)(t0 * 64 + row) * DD + c * 8);
    rv[i] = *(const short8*)(Vp + (size_t)row * TT + t0 * 64 + c * 8);
  }
#pragma unroll
  for (int i = 0; i < 2; ++i) {
    int idx = tid + i * 256;
    int row = idx >> 3, c = idx & 7;
    int off = row * 64 + ((c ^ (row & 7)) * 8);
    *(short8*)(&Ks[0][off]) = rk[i];
    *(short8*)(&Vs[0][off]) = rv[i];
  }

  int buf = 0;
  for (int t = t0; t < t1; ++t) {
    __syncthreads();
    int kvb = t * 64;
    bool havenext = (t + 1 < t1);
    if (havenext) {
      int kvb2 = (t + 1) * 64;
#pragma unroll
      for (int i = 0; i < 2; ++i) {
        int idx = tid + i * 256;
        int row = idx >> 3, c = idx & 7;
        rk[i] = *(const short8*)(Kp + (size_t)(kvb2 + row) * DD + c * 8);
        rv[i] = *(const short8*)(Vp + (size_t)row * TT + kvb2 + c * 8);
      }
    }

    if (kvb <= q0 + 31) {
      f32x16 st[2];
      __builtin_amdgcn_s_setprio(1);
#pragma unroll
      for (int t32 = 0; t32 < 2; ++t32) {
        int row = t32 * 32 + l31;
        {
          int off = row * 64 + ((h ^ (row & 7)) * 8);
          short8 kf = *(const short8*)(&Ks[buf][off]);
          st[t32] = __builtin_amdgcn_mfma_f32_32x32x16_bf16(kf, qf[0], zv, 0, 0, 0);
        }
#pragma unroll
        for (int m = 1; m < 4; ++m) {
          int off = row * 64 + (((2 * m + h) ^ (row & 7)) * 8);
          short8 kf = *(const short8*)(&Ks[buf][off]);
          st[t32] = __builtin_amdgcn_mfma_f32_32x32x16_bf16(kf, qf[m], st[t32], 0, 0, 0);
        }
      }
      __builtin_amdgcn_s_setprio(0);

      if (kvb + 63 > q0) {
#pragma unroll
        for (int t32 = 0; t32 < 2; ++t32)
#pragma unroll
          for (int r = 0; r < 16; ++r) {
            int kvg = kvb + t32 * 32 + (r & 3) + 8 * (r >> 2) + 4 * h;
            if (kvg > qrow) st[t32][r] = -1e30f;
          }
      }

      // row max: 4-chain v_max3 tree over 32 values, then cross-half
      float A = st[0][0], B = st[0][1], C = st[0][2], Dv = st[0][3];
#pragma unroll
      for (int r = 4; r < 16; r += 4) {
        A = fmax3(A, st[0][r], st[0][r + 1]);
        B = fmax3(B, st[0][r + 2], st[0][r + 3]);
        C = fmax3(C, st[1][r - 4], st[1][r - 3]);
        Dv = fmax3(Dv, st[1][r - 2], st[1][r - 1]);
      }
      C = fmax3(C, st[1][12], st[1][13]);
      Dv = fmax3(Dv, st[1][14], st[1][15]);
      float mx = fmaxf(fmax3(A, B, C), Dv);
      mx = fmaxf(mx, __shfl_xor(mx, 32));

      if (__any(mx - mrun > 8.0f)) {     // log2 units
        float mnew = fmaxf(mrun, mx);
        float alpha = fexp2(mrun - mnew);
        lrun *= alpha;
#pragma unroll
        for (int dt = 0; dt < 2; ++dt)
#pragma unroll
          for (int r = 0; r < 16; ++r) po[dt][r] *= alpha;
        mrun = mnew;
      }

      float sum = 0.0f;
#pragma unroll
      for (int t32 = 0; t32 < 2; ++t32)
#pragma unroll
        for (int r = 0; r < 16; ++r) {
          float p = fexp2(st[t32][r] - mrun);
          st[t32][r] = p;
          sum += p;
        }
      sum += __shfl_xor(sum, 32);
      lrun += sum;

      short8 pf[4];
#pragma unroll
      for (int g = 0; g < 4; ++g) {
        int t32 = g >> 1, r0 = (g & 1) * 8;
        int a = cvtpk(st[t32][r0 + 0], st[t32][r0 + 1]);
        int b = cvtpk(st[t32][r0 + 4], st[t32][r0 + 5]);
        plswap(a, b);
        int c = cvtpk(st[t32][r0 + 2], st[t32][r0 + 3]);
        int d = cvtpk(st[t32][r0 + 6], st[t32][r0 + 7]);
        plswap(c, d);
        union { int w[4]; short8 s; } u;
        u.w[0] = a; u.w[1] = c; u.w[2] = b; u.w[3] = d;
        pf[g] = u.s;
      }

      __builtin_amdgcn_s_setprio(1);
#pragma unroll
      for (int dt = 0; dt < 2; ++dt) {
#pragma unroll
        for (int g = 0; g < 4; ++g) {
          int row = dt * 32 + l31;
          int off = row * 64 + (((2 * g + h) ^ (row & 7)) * 8);
          short8 vf = *(const short8*)(&Vs[buf][off]);
          po[dt] = __builtin_amdgcn_mfma_f32_32x32x16_bf16(vf, pf[g], po[dt], 0, 0, 0);
        }
      }
      __builtin_amdgcn_s_setprio(0);
    }

    if (havenext) {
#pragma unroll
      for (int i = 0; i < 2; ++i) {
        int idx = tid + i * 256;
        int row = idx >> 3, c = idx & 7;
        int off = row * 64 + ((c ^ (row & 7)) * 8);
        *(short8*)(&Ks[buf ^ 1][off]) = rk[i];
        *(short8*)(&Vs[buf ^ 1][off]) = rv[i];
      }
    }
    buf ^= 1;
  }

  int wrow = wid * 32 + l31;
  size_t pobase = (job * 128 + wrow) * 64;
#pragma unroll
  for (int dt = 0; dt < 2; ++dt)
#pragma unroll
    for (int r = 0; r < 16; r += 2) {
      int d = dt * 32 + (r & 3) + 8 * (r >> 2) + 4 * h;
      int w = cvtpk(po[dt][r], po[dt][r + 1]);
      *(int*)(PO + pobase + d) = w;
    }
  if (h == 0) {
    Pm[job * 128 + wrow] = mrun;
    Pl[job * 128 + wrow] = lrun;
  }
}

// ---------------- combine partials -> Yb bf16 (exp2 domain) ----------------
__global__ __launch_bounds__(256) void k_attn_combine(const unsigned short* __restrict__ PO,
                                                      const float* __restrict__ Pm,
                                                      const float* __restrict__ Pl,
                                                      unsigned short* __restrict__ Y) {
  int qt = blockIdx.x, bh = blockIdx.y;
  int nc = (qt >> 2) + 1;
  size_t job0 = (size_t)bh * NJOBS + jbase(qt);
  int tid = threadIdx.x;
  int row = tid >> 1, half = tid & 1;

  float m[4], l[4];
  float M = -1e30f;
  for (int c = 0; c < nc; ++c) {
    m[c] = Pm[(job0 + c) * 128 + row];
    l[c] = Pl[(job0 + c) * 128 + row];
    M = fmaxf(M, m[c]);
  }
  float L = 0.0f, w[4];
  for (int c = 0; c < nc; ++c) {
    w[c] = fexp2(m[c] - M);
    L += l[c] * w[c];
  }
  float inv = 1.0f / L;

  float acc[32];
#pragma unroll
  for (int j = 0; j < 32; ++j) acc[j] = 0.0f;
  for (int c = 0; c < nc; ++c) {
    const unsigned short* p = PO + ((job0 + c) * 128 + row) * 64 + half * 32;
    float wc = w[c];
#pragma unroll
    for (int k = 0; k < 4; ++k) {
      short8 v = *(const short8*)(p + k * 8);
#pragma unroll
      for (int j = 0; j < 8; ++j) acc[k * 8 + j] += wc * bf2f((unsigned short)v[j]);
    }
  }
  int b = bh >> 4, hh = bh & 15;
  int t = qt * 128 + row;
  unsigned short* yp = Y + ((size_t)(b * TT + t)) * CCH + hh * DD + half * 32;
#pragma unroll
  for (int k = 0; k < 4; ++k) {
    short8 wv;
#pragma unroll
    for (int j = 0; j < 8; ++j) wv[j] = (short)f2bf(acc[k * 8 + j] * inv);
    *(short8*)(yp + k * 8) = wv;
  }
}

// ---------------- proj GEMM (m97 pattern): Yb bf16 @ Wt_proj bf16 + bias -> f32 out ----------------
__global__ __launch_bounds__(256) void k_proj_gemm(const unsigned short* __restrict__ Yb,
                                                   const unsigned short* __restrict__ Wt,
                                                   const float* __restrict__ bias,
                                                   float* __restrict__ Out) {
  __shared__ __align__(16) unsigned short As[128 * 32];
  __shared__ __align__(16) unsigned short Bs[128 * 32];
  int tid = threadIdx.x;
  int mb = blockIdx.x * 128;
  int nb = blockIdx.y * 128;
  int wid = tid >> 6, lane = tid & 63;
  int wr = (wid >> 1) * 64, wc = (wid & 1) * 64;
  int l15 = lane & 15, l4 = lane >> 4;
  int l16 = lane >> 2, lc = (lane & 3) * 8;
  f32x4 acc[4][4];
#pragma unroll
  for (int a = 0; a < 4; ++a)
#pragma unroll
    for (int b = 0; b < 4; ++b)
#pragma unroll
      for (int j = 0; j < 4; ++j) acc[a][b][j] = 0.0f;

  for (int kb = 0; kb < CCH; kb += 32) {
#pragma unroll
    for (int i = 0; i < 2; ++i) {
      int arow = wid * 32 + i * 16;
      gload_lds16(Yb + (size_t)(mb + arow + l16) * CCH + kb + lc, &As[arow * 32]);
      gload_lds16(Wt + (size_t)(nb + arow + l16) * CCH + kb + lc, &Bs[arow * 32]);
    }
    __syncthreads();
    short8 af[4], bfr[4];
#pragma unroll
    for (int mt = 0; mt < 4; ++mt) af[mt] = *(const short8*)(&As[(wr + mt * 16 + l15) * 32 + l4 * 8]);
#pragma unroll
    for (int nt = 0; nt < 4; ++nt) bfr[nt] = *(const short8*)(&Bs[(wc + nt * 16 + l15) * 32 + l4 * 8]);
#pragma unroll
    for (int mt = 0; mt < 4; ++mt)
#pragma unroll
      for (int nt = 0; nt < 4; ++nt)
        acc[mt][nt] = __builtin_amdgcn_mfma_f32_16x16x32_bf16(af[mt], bfr[nt], acc[mt][nt], 0, 0, 0);
    __syncthreads();
  }

#pragma unroll
  for (int mt = 0; mt < 4; ++mt) {
#pragma unroll
    for (int nt = 0; nt < 4; ++nt) {
      int gcol = nb + wc + nt * 16 + l15;
      float bv = bias[gcol];
#pragma unroll
      for (int j = 0; j < 4; ++j) {
        int grow = mb + wr + mt * 16 + l4 * 4 + j;
        Out[(size_t)grow * CCH + gcol] = acc[mt][nt][j] + bv;
      }
    }
  }
}

extern "C" void kernel_launch(void* const* d_in, const int* in_sizes, int n_in,
                              void* d_out, int out_size, void* d_ws, size_t ws_size,
                              hipStream_t stream) {
  const float* x      = (const float*)d_in[0];
  const float* W_qkv  = (const float*)d_in[1];
  const float* b_qkv  = (const float*)d_in[2];
  const float* W_proj = (const float*)d_in[3];
  const float* b_proj = (const float*)d_in[4];
  float* out = (float*)d_out;

  char* ws = (char*)d_ws;
  size_t off = 0;
  unsigned short* Wt_qkv  = (unsigned short*)(ws + off); off += (size_t)N3 * CCH * 2;   // 6.3 MB
  unsigned short* Wt_proj = (unsigned short*)(ws + off); off += (size_t)CCH * CCH * 2;  // 2.1 MB
  unsigned short* Xb      = (unsigned short*)(ws + off); off += (size_t)BT * CCH * 2;   // 8.4 MB
  unsigned short* Qb      = (unsigned short*)(ws + off); off += (size_t)BT * CCH * 2;   // 8.4 MB
  unsigned short* Kb      = (unsigned short*)(ws + off); off += (size_t)BT * CCH * 2;   // 8.4 MB
  unsigned short* Vt      = (unsigned short*)(ws + off); off += (size_t)BT * CCH * 2;   // 8.4 MB
  unsigned short* Yb      = (unsigned short*)(ws + off); off += (size_t)BT * CCH * 2;   // 8.4 MB
  unsigned short* PO      = (unsigned short*)(ws + off); off += (size_t)32 * NJOBS * 128 * 64 * 2; // 21 MB
  float*          Pm      = (float*)(ws + off);          off += (size_t)32 * NJOBS * 128 * 4;
  float*          Pl      = (float*)(ws + off);          off += (size_t)32 * NJOBS * 128 * 4;

  k_convert<<<dim3(BT * CCH / 8 / 256), 256, 0, stream>>>(x, Xb, BT * CCH / 8);
  k_transpose_cvt<<<dim3(N3 / 32, CCH / 32), 256, 0, stream>>>(W_qkv, Wt_qkv, CCH, N3);
  k_transpose_cvt<<<dim3(CCH / 32, CCH / 32), 256, 0, stream>>>(W_proj, Wt_proj, CCH, CCH);
  k_qkv_gemm<<<dim3(BT / 128, N3 / 128), 256, 0, stream>>>(Xb, Wt_qkv, b_qkv, Qb, Kb, Vt);
  k_attn<<<dim3(NJOBS, BB * HH), 256, 0, stream>>>(Qb, Kb, Vt, PO, Pm, Pl);
  k_attn_combine<<<dim3(TT / 128, BB * HH), 256, 0, stream>>>(PO, Pm, Pl, Yb);
  k_proj_gemm<<<dim3(BT / 128, CCH / 128), 256, 0, stream>>>(Yb, Wt_proj, b_proj, out);
}